// Round 1
// baseline (1378.729 us; speedup 1.0000x reference)
//
#include <hip/hip_runtime.h>
#include <math.h>

#define NB    2048
#define THIST 15
#define DD    64
#define HH    128
#define NSEG  20
#define MAXIT 48

// DOPRI coefficients (rounded to f32 exactly as jnp weak-typing does)
#define cA21 ((float)0.161)
#define cA31 ((float)-0.008480655492356989)
#define cA32 ((float)0.335480655492357)
#define cA41 ((float)2.8971530571054935)
#define cA42 ((float)-6.359448489975075)
#define cA43 ((float)4.3622954328695815)
#define cA51 ((float)5.325864828439257)
#define cA52 ((float)-11.748883564062828)
#define cA53 ((float)7.4955393428898365)
#define cA54 ((float)-0.09249506636175525)
#define cA61 ((float)5.86145544294642)
#define cA62 ((float)-12.92096931784711)
#define cA63 ((float)8.159367898576159)
#define cA64 ((float)-0.071584973281401)
#define cA65 ((float)-0.028269050394068383)
#define cB1  ((float)0.09646076681806523)
#define cB2  ((float)0.01)
#define cB3  ((float)0.4798896504144996)
#define cB4  ((float)1.379008574103742)
#define cB5  ((float)-3.290069515436081)
#define cB6  ((float)2.324710524099774)
#define cE1  ((float)-0.001780011052225777)
#define cE2  ((float)-0.0008164344596567469)
#define cE3  ((float)0.007880878010261995)
#define cE4  ((float)-0.1447110071732629)
#define cE5  ((float)0.5823571654525552)
#define cE6  ((float)-0.45808210592918697)
#define cE7  ((float)0.015151515151515152)

struct Smem {
    float w1t[DD * HH];   // [d][j]        : W1t[d*128 + j] = W1[j][d]
    float w2t[HH * HH];   // [k][j]        : W2t[k*128 + j] = W2[j][k]
    float w3tp[DD * HH];  // [k>>1][d][k&1]: idx = (k>>1)*128 + d*2 + (k&1) = W3[d][k]
    float b1s[HH];
    float b2s[HH];
    float b3s[DD];
};

__device__ __forceinline__ float bcast(float v, int l) {
    return __int_as_float(__builtin_amdgcn_readlane(__float_as_int(v), l));
}

__device__ __forceinline__ float softplus_f(float x) {
    // jax.nn.softplus == logaddexp(x,0) == max(x,0) + log1p(exp(-|x|))
    return fmaxf(x, 0.0f) + log1pf(expf(-fabsf(x)));
}

// One MLP eval. lane = d index of this thread's state element. yv: per-lane y[lane].
__device__ __forceinline__ float mlp(const Smem& sm, float yv, int lane) {
    const float2* w1 = (const float2*)sm.w1t;   // [d*64 + lane] -> W1t[d][2l..2l+1]
    const float2* w2 = (const float2*)sm.w2t;   // [k*64 + lane]
    const float2* w3 = (const float2*)sm.w3tp;  // [m*64 + lane] -> W3[lane][2m..2m+1]
    const float2* b1v = (const float2*)sm.b1s;
    const float2* b2v = (const float2*)sm.b2s;

    // Layer 1: h1[j] = softplus(sum_d y[d]*W1[j][d] + b1[j]); lane holds j=2l,2l+1
    float2 bb = b1v[lane];
    float a0 = bb.x, a1 = bb.y;
#pragma unroll 4
    for (int d = 0; d < DD; ++d) {
        float sv = bcast(yv, d);
        float2 w = w1[d * 64 + lane];
        a0 = fmaf(sv, w.x, a0);
        a1 = fmaf(sv, w.y, a1);
    }
    float h1a = softplus_f(a0);   // h1[2*lane]
    float h1b = softplus_f(a1);   // h1[2*lane+1]

    // Layer 2: h2[j] = softplus(sum_k h1[k]*W2[j][k] + b2[j])
    float2 cb = b2v[lane];
    float c0 = cb.x, c1 = cb.y;
#pragma unroll 4
    for (int m = 0; m < 64; ++m) {
        float s0 = bcast(h1a, m);          // h1[2m]
        float s1 = bcast(h1b, m);          // h1[2m+1]
        float2 wA = w2[(2 * m) * 64 + lane];
        float2 wB = w2[(2 * m + 1) * 64 + lane];
        c0 = fmaf(s0, wA.x, c0);
        c1 = fmaf(s0, wA.y, c1);
        c0 = fmaf(s1, wB.x, c0);
        c1 = fmaf(s1, wB.y, c1);
    }
    float h2a = softplus_f(c0);
    float h2b = softplus_f(c1);

    // Layer 3: out[d] = sum_k h2[k]*W3[d][k] + b3[d]; lane holds d=lane
    float o = sm.b3s[lane];
#pragma unroll 4
    for (int m = 0; m < 64; ++m) {
        float s0 = bcast(h2a, m);
        float s1 = bcast(h2b, m);
        float2 w = w3[m * 64 + lane];
        o = fmaf(s0, w.x, o);
        o = fmaf(s1, w.y, o);
    }
    return o;
}

__global__ __launch_bounds__(512)
void ode_kernel(const float* __restrict__ history,
                const float* __restrict__ W1, const float* __restrict__ b1,
                const float* __restrict__ W2, const float* __restrict__ b2,
                const float* __restrict__ W3, const float* __restrict__ b3,
                float* __restrict__ out) {
    __shared__ Smem sm;
    const int tid = threadIdx.x;

    // Stage weights (transposed) into LDS. Global reads coalesced.
    for (int i = tid; i < DD * HH; i += 512) {       // W1: (H=128, D=64) row-major
        int j = i >> 6, d = i & 63;
        sm.w1t[d * HH + j] = W1[i];
    }
    for (int i = tid; i < HH * HH; i += 512) {       // W2: (128,128)
        int j = i >> 7, k = i & 127;
        sm.w2t[k * HH + j] = W2[i];
    }
    for (int i = tid; i < DD * HH; i += 512) {       // W3: (D=64, H=128)
        int d = i >> 7, k = i & 127;
        sm.w3tp[(k >> 1) * HH + d * 2 + (k & 1)] = W3[i];
    }
    for (int i = tid; i < HH; i += 512) { sm.b1s[i] = b1[i]; sm.b2s[i] = b2[i]; }
    for (int i = tid; i < DD; i += 512) { sm.b3s[i] = b3[i]; }
    __syncthreads();

    const int wave = tid >> 6;
    const int lane = tid & 63;
    const int b = blockIdx.x * 8 + wave;
    if (b >= NB) return;

    float yv = history[b * (THIST * DD) + (THIST - 1) * DD + lane];
    float dt = 0.1f;
    float* outb = out + b * (NSEG * DD);

    for (int seg = 1; seg <= NSEG; ++seg) {
        const float t1f = (float)seg;
        float t = t1f - 1.0f;
        bool done = false;

        for (int it = 0; it < MAXIT && !done; ++it) {
            float dt_c = fminf(dt, t1f - t);
            float h = dt_c;

            float k1 = 0.f, k2 = 0.f, k3 = 0.f, k4 = 0.f, k5 = 0.f, k6 = 0.f, k7 = 0.f;
            float y5 = 0.f;
#pragma unroll 1
            for (int st = 0; st < 7; ++st) {
                float sum;
                switch (st) {
                    case 0: sum = 0.0f; break;
                    case 1: sum = cA21 * k1; break;
                    case 2: sum = fmaf(cA31, k1, cA32 * k2); break;
                    case 3: sum = fmaf(cA41, k1, fmaf(cA42, k2, cA43 * k3)); break;
                    case 4: sum = fmaf(cA51, k1, fmaf(cA52, k2, fmaf(cA53, k3, cA54 * k4))); break;
                    case 5: sum = fmaf(cA61, k1, fmaf(cA62, k2, fmaf(cA63, k3, fmaf(cA64, k4, cA65 * k5)))); break;
                    default: sum = fmaf(cB1, k1, fmaf(cB2, k2, fmaf(cB3, k3, fmaf(cB4, k4, fmaf(cB5, k5, cB6 * k6))))); break;
                }
                float arg = fmaf(h, sum, yv);
                if (st == 6) y5 = arg;
                float kv = mlp(sm, arg, lane);
                switch (st) {
                    case 0: k1 = kv; break;
                    case 1: k2 = kv; break;
                    case 2: k3 = kv; break;
                    case 3: k4 = kv; break;
                    case 4: k5 = kv; break;
                    case 5: k6 = kv; break;
                    default: k7 = kv; break;
                }
            }

            float esum = fmaf(cE1, k1, fmaf(cE2, k2, fmaf(cE3, k3,
                         fmaf(cE4, k4, fmaf(cE5, k5, fmaf(cE6, k6, cE7 * k7))))));
            float err = h * esum;
            float sc = fmaf(1e-3f, fmaxf(fabsf(yv), fabsf(y5)), 1e-6f);
            float r = err / sc;
            float rr = r * r;
#pragma unroll
            for (int off = 32; off > 0; off >>= 1) rr += __shfl_xor(rr, off, 64);
            float err_norm = sqrtf(rr * (1.0f / 64.0f));

            bool accept = (err_norm <= 1.0f);     // loop precondition: !done
            float fac = 0.9f * powf(fmaxf(err_norm, 1e-10f), -0.2f);
            fac = fminf(fmaxf(fac, 0.2f), 10.0f);

            if (accept) { t = t + dt_c; yv = y5; }
            dt = dt_c * fac;
            done = (t >= t1f - 1e-8f);
        }

        outb[(seg - 1) * DD + lane] = yv;
    }
}

extern "C" void kernel_launch(void* const* d_in, const int* in_sizes, int n_in,
                              void* d_out, int out_size, void* d_ws, size_t ws_size,
                              hipStream_t stream) {
    const float* history = (const float*)d_in[0];
    const float* W1 = (const float*)d_in[1];
    const float* b1 = (const float*)d_in[2];
    const float* W2 = (const float*)d_in[3];
    const float* b2 = (const float*)d_in[4];
    const float* W3 = (const float*)d_in[5];
    const float* b3 = (const float*)d_in[6];
    float* out = (float*)d_out;

    ode_kernel<<<dim3(NB / 8), dim3(512), 0, stream>>>(history, W1, b1, W2, b2, W3, b3, out);
}